// Round 1
// baseline (14260.597 us; speedup 1.0000x reference)
//
#include <hip/hip_runtime.h>
#include <hip/hip_bf16.h>

// =====================================================================
// PC-RNN on MI355X.
// Math restructure:
//   Wq = Wo^T Wo  (time-invariant, 512x512)
//   u_t = (b_o - x_t) @ Wo   (precomputed for all t, parallel GEMM)
// Sequential loop per step (critical path = 2 big matvecs):
//   th = tanh(h);  h_prior = 0.9 h + 0.1(th@Wr^T + c@Wc^T + b_r)
//   tp = tanh(h_prior);  g = tp@Wq + u_t
//   e_h = 0.1(1-tp^2) g;  h = h_prior - e_h;  c -= 0.1 (e_h@Wc)
//   store tp  (errors_t = tp@Wo^T + b_o - x_t computed post-loop GEMM)
// Sharding: 32 row-groups (8 batch rows) x 8 blocks; block owns 64-state
// slice, weights LDS-resident (~159KB -> 1 block/CU). 2 agent-scope group
// barriers/step; exchange via global ws. Cooperative launch for residency.
// =====================================================================

#define TSEQ 512
#define NBAT 256
#define NOUT 256
#define NCAU 64
#define NST  512

typedef __attribute__((ext_vector_type(8))) short short8;
typedef __attribute__((ext_vector_type(4))) float floatx4;

__device__ __forceinline__ unsigned short f2b(float f) {
    union { float f; unsigned u; } v; v.f = f;
    unsigned r = v.u + 0x7FFFu + ((v.u >> 16) & 1u);
    return (unsigned short)(r >> 16);
}
__device__ __forceinline__ float b2f(unsigned short s) {
    union { unsigned u; float f; } v; v.u = ((unsigned)s) << 16;
    return v.f;
}

// ---------------- ws layout (bytes) ----------------
#define SZ_UTP ((size_t)TSEQ * NBAT * NST * 2)        // u then tp, bf16
#define OFF_UTP ((size_t)0)
#define OFF_WQ  (OFF_UTP + SZ_UTP)                    // Wq bf16 512x512
#define OFF_THX (OFF_WQ + (size_t)NST * NST * 2)      // th exchange [32][8][512] bf16
#define OFF_TPX (OFF_THX + (size_t)32 * 8 * NST * 2)  // tp exchange
#define OFF_DCX (OFF_TPX + (size_t)32 * 8 * NST * 2)  // dc partials [32][8][8][64] f32
#define OFF_CTR (OFF_DCX + (size_t)32 * 8 * 8 * 64 * 4) // barrier counters
#define SZ_ZERO ((size_t)32 * 8 * NST * 2 * 2 + (size_t)32 * 8 * 8 * 64 * 4 + (size_t)64 * 64 * 4)

// ---------------- Wq = Wo^T Wo ----------------
__global__ __launch_bounds__(256) void wq_kernel(const float* __restrict__ w_o,
                                                 unsigned short* __restrict__ wqo) {
    int idx = blockIdx.x * 256 + threadIdx.x;   // 512*512 outputs
    int i = idx >> 9, j = idx & 511;
    float s = 0.f;
    for (int o = 0; o < NOUT; ++o)
        s += w_o[(size_t)o * NST + i] * w_o[(size_t)o * NST + j];
    wqo[idx] = f2b(s);
}

// ---------------- u_t = (b_o - x_t) @ Wo : M=131072,K=256,N=512 ----------------
__global__ __launch_bounds__(256) void u_gemm(const float* __restrict__ x,
                                              const float* __restrict__ w_o,
                                              const float* __restrict__ b_o,
                                              unsigned short* __restrict__ u) {
    __shared__ __align__(16) unsigned short As[64 * 72];
    __shared__ __align__(16) unsigned short Bs[64 * 72];
    const int m0 = blockIdx.x * 64, n0 = blockIdx.y * 64;
    const int tid = threadIdx.x;
    const int w = tid >> 6, l = tid & 63, lm = l & 15, lq = l >> 4;
    floatx4 acc[4] = { {0,0,0,0}, {0,0,0,0}, {0,0,0,0}, {0,0,0,0} };
    for (int k0 = 0; k0 < NOUT; k0 += 64) {
        __syncthreads();
        {   // A[m][k] = b_o[k] - x[m][k]
            int r = tid >> 2, kk = (tid & 3) * 16;
            const float* src = x + (size_t)(m0 + r) * NOUT + k0 + kk;
            #pragma unroll
            for (int i = 0; i < 16; ++i)
                As[r * 72 + kk + i] = f2b(b_o[k0 + kk + i] - src[i]);
        }
        {   // B[n][k] = Wo[k][n]
            int kr = tid >> 2, nn = (tid & 3) * 16;
            const float* src = w_o + (size_t)(k0 + kr) * NST + n0 + nn;
            #pragma unroll
            for (int i = 0; i < 16; ++i)
                Bs[(nn + i) * 72 + kr] = f2b(src[i]);
        }
        __syncthreads();
        #pragma unroll
        for (int kt = 0; kt < 2; ++kt) {
            short8 a = *reinterpret_cast<const short8*>(&As[(w * 16 + lm) * 72 + kt * 32 + lq * 8]);
            #pragma unroll
            for (int nt = 0; nt < 4; ++nt) {
                short8 b = *reinterpret_cast<const short8*>(&Bs[(nt * 16 + lm) * 72 + kt * 32 + lq * 8]);
                acc[nt] = __builtin_amdgcn_mfma_f32_16x16x32_bf16(a, b, acc[nt], 0, 0, 0);
            }
        }
    }
    #pragma unroll
    for (int nt = 0; nt < 4; ++nt)
        #pragma unroll
        for (int q = 0; q < 4; ++q) {
            int row = m0 + w * 16 + lq * 4 + q, col = n0 + nt * 16 + lm;
            u[(size_t)row * NST + col] = f2b(acc[nt][q]);
        }
}

// ---------------- errors = tp@Wo^T + b_o - x : M=131072,K=512,N=256 ----------------
__global__ __launch_bounds__(256) void err_gemm(const unsigned short* __restrict__ tpA,
                                                const float* __restrict__ w_o,
                                                const float* __restrict__ b_o,
                                                const float* __restrict__ x,
                                                float* __restrict__ out) {
    __shared__ __align__(16) unsigned short As[64 * 72];
    __shared__ __align__(16) unsigned short Bs[64 * 72];
    const int m0 = blockIdx.x * 64, n0 = blockIdx.y * 64;
    const int tid = threadIdx.x;
    const int w = tid >> 6, l = tid & 63, lm = l & 15, lq = l >> 4;
    floatx4 acc[4] = { {0,0,0,0}, {0,0,0,0}, {0,0,0,0}, {0,0,0,0} };
    for (int k0 = 0; k0 < NST; k0 += 64) {
        __syncthreads();
        {   // A = tp (bf16)
            int r = tid >> 2, kk = (tid & 3) * 16;
            const uint4* src = reinterpret_cast<const uint4*>(tpA + (size_t)(m0 + r) * NST + k0 + kk);
            uint4* dst = reinterpret_cast<uint4*>(&As[r * 72 + kk]);
            dst[0] = src[0]; dst[1] = src[1];
        }
        {   // B[n=o][k=s] = Wo[o][s]
            int nr = tid >> 2, kk = (tid & 3) * 16;
            const float* src = w_o + (size_t)(n0 + nr) * NST + k0 + kk;
            #pragma unroll
            for (int i = 0; i < 16; ++i)
                Bs[nr * 72 + kk + i] = f2b(src[i]);
        }
        __syncthreads();
        #pragma unroll
        for (int kt = 0; kt < 2; ++kt) {
            short8 a = *reinterpret_cast<const short8*>(&As[(w * 16 + lm) * 72 + kt * 32 + lq * 8]);
            #pragma unroll
            for (int nt = 0; nt < 4; ++nt) {
                short8 b = *reinterpret_cast<const short8*>(&Bs[(nt * 16 + lm) * 72 + kt * 32 + lq * 8]);
                acc[nt] = __builtin_amdgcn_mfma_f32_16x16x32_bf16(a, b, acc[nt], 0, 0, 0);
            }
        }
    }
    #pragma unroll
    for (int nt = 0; nt < 4; ++nt)
        #pragma unroll
        for (int q = 0; q < 4; ++q) {
            int row = m0 + w * 16 + lq * 4 + q, col = n0 + nt * 16 + lm;
            out[(size_t)row * NOUT + col] = acc[nt][q] + b_o[col] - x[(size_t)row * NOUT + col];
        }
}

// ---------------- group barrier (agent scope) ----------------
__device__ __forceinline__ void gbar(unsigned* c, unsigned target) {
    __syncthreads();
    if (threadIdx.x == 0) {
        __threadfence();
        __hip_atomic_fetch_add(c, 1u, __ATOMIC_RELEASE, __HIP_MEMORY_SCOPE_AGENT);
        while (__hip_atomic_load(c, __ATOMIC_ACQUIRE, __HIP_MEMORY_SCOPE_AGENT) < target)
            __builtin_amdgcn_s_sleep(4);
    }
    __syncthreads();
}

// ---------------- persistent sequential loop ----------------
__global__ __launch_bounds__(256, 1) void loop_kernel(
    const float* __restrict__ c_init, const float* __restrict__ h_init,
    const float* __restrict__ w_r, const float* __restrict__ b_r,
    const float* __restrict__ w_c,
    unsigned short* __restrict__ utp, const unsigned short* __restrict__ wq,
    unsigned short* __restrict__ thx, unsigned short* __restrict__ tpx,
    float* __restrict__ dcx, unsigned* __restrict__ ctr) {
    // LDS: Wr frags 64K, Wq frags 64K, Wc frags 8K, Wc raw 8K,
    //      stage 8.3K, errS 2.2K, cS 1.2K  => ~159KB -> 1 block/CU
    __shared__ __align__(16) short wrF[32768];
    __shared__ __align__(16) short wqF[32768];
    __shared__ __align__(16) short wcF[4096];
    __shared__ __align__(16) unsigned short wcR[4096];
    __shared__ __align__(16) unsigned short stage[8 * 520];
    __shared__ __align__(16) float errS[8 * 68];
    __shared__ __align__(16) unsigned short cS[8 * 72];

    const int tid = threadIdx.x;
    const int bid = blockIdx.x;
    const int r8 = bid & 7, j32 = bid >> 3;
    const int member = j32 & 7;          // which 64-state slice
    const int grp = r8 * 4 + (j32 >> 3); // row-group [0,32): rows grp*8..grp*8+7
    const int rows0 = grp * 8;
    const int w = tid >> 6, l = tid & 63, lm = l & 15, lq = l >> 4;
    const int jloc = w * 16 + lm;            // local state col [0,64)
    const int jglob = member * 64 + jloc;    // global state [0,512)

    unsigned* ctrA = ctr + (size_t)(grp * 2 + 0) * 64;
    unsigned* ctrB = ctr + (size_t)(grp * 2 + 1) * 64;

    // ---- prologue: format weights into B-fragment layout in LDS ----
    for (int idx = tid; idx < 4096; idx += 256) {
        int lane = idx & 63, kt = (idx >> 6) & 15, nt = idx >> 10;
        int s = member * 64 + nt * 16 + (lane & 15);
        int k = kt * 32 + (lane >> 4) * 8;
        const float* src = w_r + (size_t)s * NST + k;
        short8 v;
        #pragma unroll
        for (int jj = 0; jj < 8; ++jj) v[jj] = (short)f2b(src[jj]);
        *reinterpret_cast<short8*>(&wrF[((nt * 16 + kt) * 64 + lane) * 8]) = v;
        short8 v2 = *reinterpret_cast<const short8*>(wq + (size_t)s * NST + k);
        *reinterpret_cast<short8*>(&wqF[((nt * 16 + kt) * 64 + lane) * 8]) = v2;
    }
    for (int idx = tid; idx < 512; idx += 256) {
        int lane = idx & 63, kt2 = (idx >> 6) & 1, wv = idx >> 7;
        int j = member * 64 + wv * 16 + (lane & 15);
        int k = kt2 * 32 + (lane >> 4) * 8;
        const float* src = w_c + (size_t)j * NCAU + k;
        short8 v;
        #pragma unroll
        for (int jj = 0; jj < 8; ++jj) v[jj] = (short)f2b(src[jj]);
        *reinterpret_cast<short8*>(&wcF[((wv * 2 + kt2) * 64 + lane) * 8]) = v;
    }
    for (int idx = tid; idx < 4096; idx += 256)
        wcR[idx] = f2b(w_c[(size_t)(member * 64 + (idx >> 6)) * NCAU + (idx & 63)]);

    const float br_l = b_r[jglob];
    float hP[4] = {0.f, 0.f, 0.f, 0.f};    // h_post; rows = lq*4+q (real only l<32)
    if (l < 32) {
        #pragma unroll
        for (int q = 0; q < 4; ++q)
            hP[q] = h_init[(size_t)(rows0 + lq * 4 + q) * NST + jglob];
    }
    const int cr = tid >> 5, cc = (tid * 2) & 63;  // c master: 2 elems/thread
    float cM0 = c_init[(size_t)(rows0 + cr) * NCAU + cc];
    float cM1 = c_init[(size_t)(rows0 + cr) * NCAU + cc + 1];

    if (l < 32) {
        #pragma unroll
        for (int q = 0; q < 4; ++q)
            thx[(size_t)grp * 8 * NST + (lq * 4 + q) * NST + jglob] = f2b(tanhf(hP[q]));
    }
    gbar(ctrA, 8u);

    for (int s = 0; s < TSEQ; ++s) {
        // u prefetch (slots later overwritten by tp from the same thread)
        float uR[4] = {0.f, 0.f, 0.f, 0.f};
        if (l < 32) {
            #pragma unroll
            for (int q = 0; q < 4; ++q)
                uR[q] = b2f(utp[((size_t)(s * NBAT + rows0 + lq * 4 + q)) * NST + jglob]);
        }
        // c update from partials published before previous barrier A
        {
            float d0 = 0.f, d1 = 0.f;
            #pragma unroll
            for (int mm = 0; mm < 8; ++mm) {
                const float* dp = dcx + (((size_t)(grp * 8 + mm) * 8 + cr) * 64 + cc);
                d0 += dp[0]; d1 += dp[1];
            }
            cM0 -= 0.1f * d0; cM1 -= 0.1f * d1;
            cS[cr * 72 + cc] = f2b(cM0);
            cS[cr * 72 + cc + 1] = f2b(cM1);
        }
        // stage full th (8x512 bf16) from exchange buffer
        {
            int row = tid >> 5, ch = tid & 31;
            const uint4* src = reinterpret_cast<const uint4*>(thx + (size_t)grp * 8 * NST + row * NST + ch * 16);
            uint4* dst = reinterpret_cast<uint4*>(&stage[row * 520 + ch * 16]);
            dst[0] = src[0]; dst[1] = src[1];
        }
        __syncthreads();
        // M1: h_prior slice = 0.9h + 0.1(th@Wr^T + c@Wc^T + b_r)
        floatx4 acc = {0.f, 0.f, 0.f, 0.f};
        #pragma unroll
        for (int kt = 0; kt < 16; ++kt) {
            short8 a = {0, 0, 0, 0, 0, 0, 0, 0};
            if (lm < 8) a = *reinterpret_cast<const short8*>(&stage[lm * 520 + kt * 32 + lq * 8]);
            short8 b = *reinterpret_cast<const short8*>(&wrF[((w * 16 + kt) * 64 + l) * 8]);
            acc = __builtin_amdgcn_mfma_f32_16x16x32_bf16(a, b, acc, 0, 0, 0);
        }
        #pragma unroll
        for (int kt = 0; kt < 2; ++kt) {
            short8 a = {0, 0, 0, 0, 0, 0, 0, 0};
            if (lm < 8) a = *reinterpret_cast<const short8*>(&cS[lm * 72 + kt * 32 + lq * 8]);
            short8 b = *reinterpret_cast<const short8*>(&wcF[((w * 2 + kt) * 64 + l) * 8]);
            acc = __builtin_amdgcn_mfma_f32_16x16x32_bf16(a, b, acc, 0, 0, 0);
        }
        float hPr[4], tp[4];
        #pragma unroll
        for (int q = 0; q < 4; ++q) {
            hPr[q] = 0.9f * hP[q] + 0.1f * (acc[q] + br_l);
            tp[q] = tanhf(hPr[q]);
        }
        if (l < 32) {
            #pragma unroll
            for (int q = 0; q < 4; ++q) {
                unsigned short tb = f2b(tp[q]);
                tpx[(size_t)grp * 8 * NST + (lq * 4 + q) * NST + jglob] = tb;
                utp[((size_t)(s * NBAT + rows0 + lq * 4 + q)) * NST + jglob] = tb;
            }
        }
        gbar(ctrB, 8u * (s + 1));
        // stage full tp
        {
            int row = tid >> 5, ch = tid & 31;
            const uint4* src = reinterpret_cast<const uint4*>(tpx + (size_t)grp * 8 * NST + row * NST + ch * 16);
            uint4* dst = reinterpret_cast<uint4*>(&stage[row * 520 + ch * 16]);
            dst[0] = src[0]; dst[1] = src[1];
        }
        __syncthreads();
        // M2: g slice = tp@Wq + u_t
        floatx4 ac2 = {0.f, 0.f, 0.f, 0.f};
        #pragma unroll
        for (int kt = 0; kt < 16; ++kt) {
            short8 a = {0, 0, 0, 0, 0, 0, 0, 0};
            if (lm < 8) a = *reinterpret_cast<const short8*>(&stage[lm * 520 + kt * 32 + lq * 8]);
            short8 b = *reinterpret_cast<const short8*>(&wqF[((w * 16 + kt) * 64 + l) * 8]);
            ac2 = __builtin_amdgcn_mfma_f32_16x16x32_bf16(a, b, ac2, 0, 0, 0);
        }
        float eH[4];
        #pragma unroll
        for (int q = 0; q < 4; ++q) {
            float g = ac2[q] + uR[q];
            eH[q] = 0.1f * (1.f - tp[q] * tp[q]) * g;
            hP[q] = hPr[q] - eH[q];
        }
        if (l < 32) {
            #pragma unroll
            for (int q = 0; q < 4; ++q) errS[(lq * 4 + q) * 68 + jloc] = eH[q];
        }
        __syncthreads();
        // dc partial = e_h(slice) @ Wc(slice)
        {
            float s0 = 0.f, s1 = 0.f;
            #pragma unroll 8
            for (int j = 0; j < 64; ++j) {
                float e = errS[cr * 68 + j];
                s0 += e * b2f(wcR[j * 64 + cc]);
                s1 += e * b2f(wcR[j * 64 + cc + 1]);
            }
            float* dp = dcx + (((size_t)(grp * 8 + member) * 8 + cr) * 64 + cc);
            dp[0] = s0; dp[1] = s1;
        }
        // publish th(new)
        if (l < 32) {
            #pragma unroll
            for (int q = 0; q < 4; ++q)
                thx[(size_t)grp * 8 * NST + (lq * 4 + q) * NST + jglob] = f2b(tanhf(hP[q]));
        }
        gbar(ctrA, 8u * (s + 2));
    }
}

extern "C" void kernel_launch(void* const* d_in, const int* in_sizes, int n_in,
                              void* d_out, int out_size, void* d_ws, size_t ws_size,
                              hipStream_t stream) {
    const float* x      = (const float*)d_in[0];
    const float* c_init = (const float*)d_in[1];
    const float* h_init = (const float*)d_in[2];
    const float* w_o    = (const float*)d_in[3];
    const float* b_o    = (const float*)d_in[4];
    const float* w_c    = (const float*)d_in[5];
    const float* w_r    = (const float*)d_in[6];
    const float* b_r    = (const float*)d_in[7];

    char* wsb = (char*)d_ws;
    unsigned short* utp = (unsigned short*)(wsb + OFF_UTP);
    unsigned short* wq  = (unsigned short*)(wsb + OFF_WQ);
    unsigned short* thx = (unsigned short*)(wsb + OFF_THX);
    unsigned short* tpx = (unsigned short*)(wsb + OFF_TPX);
    float*          dcx = (float*)(wsb + OFF_DCX);
    unsigned*       ctr = (unsigned*)(wsb + OFF_CTR);

    // zero exchange buffers + dc partials + barrier counters (ws is poisoned)
    hipMemsetAsync(wsb + OFF_THX, 0, SZ_ZERO, stream);

    wq_kernel<<<dim3((NST * NST) / 256), dim3(256), 0, stream>>>(w_o, wq);
    u_gemm<<<dim3((TSEQ * NBAT) / 64, NST / 64), dim3(256), 0, stream>>>(x, w_o, b_o, utp);

    void* args[] = { (void*)&c_init, (void*)&h_init, (void*)&w_r, (void*)&b_r,
                     (void*)&w_c, (void*)&utp, (void*)&wq, (void*)&thx,
                     (void*)&tpx, (void*)&dcx, (void*)&ctr };
    hipLaunchCooperativeKernel((void*)loop_kernel, dim3(256), dim3(256), args, 0, stream);

    err_gemm<<<dim3((TSEQ * NBAT) / 64, NOUT / 64), dim3(256), 0, stream>>>(utp, w_o, b_o, x, (float*)d_out);
}

// Round 3
// 3904.370 us; speedup vs baseline: 3.6525x; 3.6525x over previous
//
#include <hip/hip_runtime.h>
#include <hip/hip_bf16.h>

// =====================================================================
// PC-RNN on MI355X.
//   Wq = Wo^T Wo (precomputed);  u_t = (b_o - x_t) @ Wo (parallel GEMM)
// Loop step:  th=tanh(h); h_prior=0.9h+0.1(th@Wr^T + c@Wc^T + b_r)
//             tp=tanh(h_prior); g=tp@Wq+u_t; e=0.1(1-tp^2)g; h=h_prior-e
//             c -= 0.1 e@Wc;  store tp (errors GEMM post-loop)
// Sharding: 32 row-groups x 8 members (64-state slice each); weights
// LDS-resident (159KB -> 1 block/CU).
// R3 sync design: ALL cross-block data moves via RELAXED agent-scope
// atomics (coherence-point ops; verified semantics, no cache-flag bets).
// Ordering is structural: data stores -> __syncthreads (vmcnt(0) drain)
// -> flag store; reader: poll flag -> __syncthreads -> data loads.
// No acquire/release fences => no buffer_wbl2 / buffer_inv (R1's cost).
// No XCD assumptions (R2's hang risk).
// =====================================================================

#define TSEQ 512
#define NBAT 256
#define NOUT 256
#define NCAU 64
#define NST  512

typedef __attribute__((ext_vector_type(8))) short short8;
typedef __attribute__((ext_vector_type(4))) float floatx4;
typedef unsigned long long ull;

__device__ __forceinline__ unsigned short f2b(float f) {
    union { float f; unsigned u; } v; v.f = f;
    unsigned r = v.u + 0x7FFFu + ((v.u >> 16) & 1u);
    return (unsigned short)(r >> 16);
}
__device__ __forceinline__ float b2f(unsigned short s) {
    union { unsigned u; float f; } v; v.u = ((unsigned)s) << 16;
    return v.f;
}

#define ATOMIC_ST32(p, v) __hip_atomic_store((p), (v), __ATOMIC_RELAXED, __HIP_MEMORY_SCOPE_AGENT)
#define ATOMIC_ST64(p, v) __hip_atomic_store((p), (v), __ATOMIC_RELAXED, __HIP_MEMORY_SCOPE_AGENT)
#define ATOMIC_LD32(p)    __hip_atomic_load((p), __ATOMIC_RELAXED, __HIP_MEMORY_SCOPE_AGENT)
#define ATOMIC_LD64(p)    __hip_atomic_load((p), __ATOMIC_RELAXED, __HIP_MEMORY_SCOPE_AGENT)

// ---------------- ws layout (bytes) ----------------
#define SZ_UTP  ((size_t)TSEQ * NBAT * NST * 2)            // 134,217,728
#define OFF_UTP ((size_t)0)
#define OFF_WQ  (OFF_UTP + SZ_UTP)                         // 512*512*2
#define OFF_THX (OFF_WQ + (size_t)NST * NST * 2)           // [32][8][512] bf16
#define OFF_DCX (OFF_THX + (size_t)32 * 8 * NST * 2)       // [32][8m][8r][64c] f32
#define OFF_FLG (OFF_DCX + (size_t)32 * 8 * 8 * 64 * 4)    // 2*[32][8] flags, 128B apart
#define SZ_ZERO ((size_t)32 * 8 * NST * 2 + (size_t)32 * 8 * 8 * 64 * 4 + (size_t)2 * 32 * 8 * 32 * 4)

// ---------------- Wq = Wo^T Wo ----------------
__global__ __launch_bounds__(256) void wq_kernel(const float* __restrict__ w_o,
                                                 unsigned short* __restrict__ wqo) {
    int idx = blockIdx.x * 256 + threadIdx.x;
    int i = idx >> 9, j = idx & 511;
    float s = 0.f;
    for (int o = 0; o < NOUT; ++o)
        s += w_o[(size_t)o * NST + i] * w_o[(size_t)o * NST + j];
    wqo[idx] = f2b(s);
}

// ---------------- u_t = (b_o - x_t) @ Wo ----------------
__global__ __launch_bounds__(256) void u_gemm(const float* __restrict__ x,
                                              const float* __restrict__ w_o,
                                              const float* __restrict__ b_o,
                                              unsigned short* __restrict__ u) {
    __shared__ __align__(16) unsigned short As[64 * 72];
    __shared__ __align__(16) unsigned short Bs[64 * 72];
    const int m0 = blockIdx.x * 64, n0 = blockIdx.y * 64;
    const int tid = threadIdx.x;
    const int w = tid >> 6, l = tid & 63, lm = l & 15, lq = l >> 4;
    floatx4 acc[4] = { {0,0,0,0}, {0,0,0,0}, {0,0,0,0}, {0,0,0,0} };
    for (int k0 = 0; k0 < NOUT; k0 += 64) {
        __syncthreads();
        {
            int r = tid >> 2, kk = (tid & 3) * 16;
            const float* src = x + (size_t)(m0 + r) * NOUT + k0 + kk;
            #pragma unroll
            for (int i = 0; i < 16; ++i)
                As[r * 72 + kk + i] = f2b(b_o[k0 + kk + i] - src[i]);
        }
        {
            int kr = tid >> 2, nn = (tid & 3) * 16;
            const float* src = w_o + (size_t)(k0 + kr) * NST + n0 + nn;
            #pragma unroll
            for (int i = 0; i < 16; ++i)
                Bs[(nn + i) * 72 + kr] = f2b(src[i]);
        }
        __syncthreads();
        #pragma unroll
        for (int kt = 0; kt < 2; ++kt) {
            short8 a = *reinterpret_cast<const short8*>(&As[(w * 16 + lm) * 72 + kt * 32 + lq * 8]);
            #pragma unroll
            for (int nt = 0; nt < 4; ++nt) {
                short8 b = *reinterpret_cast<const short8*>(&Bs[(nt * 16 + lm) * 72 + kt * 32 + lq * 8]);
                acc[nt] = __builtin_amdgcn_mfma_f32_16x16x32_bf16(a, b, acc[nt], 0, 0, 0);
            }
        }
    }
    #pragma unroll
    for (int nt = 0; nt < 4; ++nt)
        #pragma unroll
        for (int q = 0; q < 4; ++q) {
            int row = m0 + w * 16 + lq * 4 + q, col = n0 + nt * 16 + lm;
            u[(size_t)row * NST + col] = f2b(acc[nt][q]);
        }
}

// ---------------- errors = tp@Wo^T + b_o - x ----------------
__global__ __launch_bounds__(256) void err_gemm(const unsigned short* __restrict__ tpA,
                                                const float* __restrict__ w_o,
                                                const float* __restrict__ b_o,
                                                const float* __restrict__ x,
                                                float* __restrict__ out) {
    __shared__ __align__(16) unsigned short As[64 * 72];
    __shared__ __align__(16) unsigned short Bs[64 * 72];
    const int m0 = blockIdx.x * 64, n0 = blockIdx.y * 64;
    const int tid = threadIdx.x;
    const int w = tid >> 6, l = tid & 63, lm = l & 15, lq = l >> 4;
    floatx4 acc[4] = { {0,0,0,0}, {0,0,0,0}, {0,0,0,0}, {0,0,0,0} };
    for (int k0 = 0; k0 < NST; k0 += 64) {
        __syncthreads();
        {
            int r = tid >> 2, kk = (tid & 3) * 16;
            const uint4* src = reinterpret_cast<const uint4*>(tpA + (size_t)(m0 + r) * NST + k0 + kk);
            uint4* dst = reinterpret_cast<uint4*>(&As[r * 72 + kk]);
            dst[0] = src[0]; dst[1] = src[1];
        }
        {
            int nr = tid >> 2, kk = (tid & 3) * 16;
            const float* src = w_o + (size_t)(n0 + nr) * NST + k0 + kk;
            #pragma unroll
            for (int i = 0; i < 16; ++i)
                Bs[nr * 72 + kk + i] = f2b(src[i]);
        }
        __syncthreads();
        #pragma unroll
        for (int kt = 0; kt < 2; ++kt) {
            short8 a = *reinterpret_cast<const short8*>(&As[(w * 16 + lm) * 72 + kt * 32 + lq * 8]);
            #pragma unroll
            for (int nt = 0; nt < 4; ++nt) {
                short8 b = *reinterpret_cast<const short8*>(&Bs[(nt * 16 + lm) * 72 + kt * 32 + lq * 8]);
                acc[nt] = __builtin_amdgcn_mfma_f32_16x16x32_bf16(a, b, acc[nt], 0, 0, 0);
            }
        }
    }
    #pragma unroll
    for (int nt = 0; nt < 4; ++nt)
        #pragma unroll
        for (int q = 0; q < 4; ++q) {
            int row = m0 + w * 16 + lq * 4 + q, col = n0 + nt * 16 + lm;
            out[(size_t)row * NOUT + col] = acc[nt][q] + b_o[col] - x[(size_t)row * NOUT + col];
        }
}

// ---------------- persistent sequential loop ----------------
__global__ __launch_bounds__(256, 1) void loop_kernel(
    const float* __restrict__ c_init, const float* __restrict__ h_init,
    const float* __restrict__ w_r, const float* __restrict__ b_r,
    const float* __restrict__ w_c,
    unsigned short* __restrict__ utp, const unsigned short* __restrict__ wq,
    unsigned short* __restrict__ thx, float* __restrict__ dcx,
    unsigned* __restrict__ flg) {
    __shared__ __align__(16) short wrF[32768];
    __shared__ __align__(16) short wqF[32768];
    __shared__ __align__(16) short wcF[4096];
    __shared__ __align__(16) unsigned short wcR[4096];
    __shared__ __align__(16) unsigned short stage[8 * 520];
    __shared__ __align__(16) float errS[8 * 68];
    __shared__ __align__(16) unsigned short cS[8 * 72];

    const int tid = threadIdx.x;
    const int bid = blockIdx.x;
    const int member = bid & 7;     // 64-state slice within group
    const int grp = bid >> 3;       // row-group [0,32): rows grp*8..grp*8+7
    const int rows0 = grp * 8;
    const int w = tid >> 6, l = tid & 63, lm = l & 15, lq = l >> 4;
    const int jloc = w * 16 + lm;
    const int jglob = member * 64 + jloc;

    unsigned* flgA = flg;                          // [32][8] x 32 dwords (128B)
    unsigned* flgB = flg + 32 * 8 * 32;
    unsigned*  thxU32 = (unsigned*)thx;
    ull*       thxU64 = (ull*)thx;
    unsigned*  utpU32 = (unsigned*)utp;
    ull*       utpU64 = (ull*)utp;
    ull*       dcU64  = (ull*)dcx;

    // ---- prologue: format weights into B-fragment layout in LDS ----
    for (int idx = tid; idx < 4096; idx += 256) {
        int lane = idx & 63, kt = (idx >> 6) & 15, nt = idx >> 10;
        int s = member * 64 + nt * 16 + (lane & 15);
        int k = kt * 32 + (lane >> 4) * 8;
        const float* src = w_r + (size_t)s * NST + k;
        short8 v;
        #pragma unroll
        for (int jj = 0; jj < 8; ++jj) v[jj] = (short)f2b(src[jj]);
        *reinterpret_cast<short8*>(&wrF[((nt * 16 + kt) * 64 + lane) * 8]) = v;
        short8 v2 = *reinterpret_cast<const short8*>(wq + (size_t)s * NST + k);
        *reinterpret_cast<short8*>(&wqF[((nt * 16 + kt) * 64 + lane) * 8]) = v2;
    }
    for (int idx = tid; idx < 512; idx += 256) {
        int lane = idx & 63, kt2 = (idx >> 6) & 1, wv = idx >> 7;
        int j = member * 64 + wv * 16 + (lane & 15);
        int k = kt2 * 32 + (lane >> 4) * 8;
        const float* src = w_c + (size_t)j * NCAU + k;
        short8 v;
        #pragma unroll
        for (int jj = 0; jj < 8; ++jj) v[jj] = (short)f2b(src[jj]);
        *reinterpret_cast<short8*>(&wcF[((wv * 2 + kt2) * 64 + lane) * 8]) = v;
    }
    for (int idx = tid; idx < 4096; idx += 256)
        wcR[idx] = f2b(w_c[(size_t)(member * 64 + (idx >> 6)) * NCAU + (idx & 63)]);

    const float br_l = b_r[jglob];
    float hP[4] = {0.f, 0.f, 0.f, 0.f};
    if (l < 32) {
        #pragma unroll
        for (int q = 0; q < 4; ++q)
            hP[q] = h_init[(size_t)(rows0 + lq * 4 + q) * NST + jglob];
    }
    const int cr = tid >> 5, cc = (tid * 2) & 63;
    float cM0 = c_init[(size_t)(rows0 + cr) * NCAU + cc];
    float cM1 = c_init[(size_t)(rows0 + cr) * NCAU + cc + 1];

    // ---- publish th(0): shuffle-pack bf16 pairs, atomic dword stores ----
    {
        unsigned pk[4];
        #pragma unroll
        for (int q = 0; q < 4; ++q) {
            unsigned m_ = f2b(tanhf(hP[q]));
            unsigned p_ = __shfl_xor(m_, 1);
            pk[q] = m_ | (p_ << 16);
        }
        if (l < 32 && !(l & 1)) {
            #pragma unroll
            for (int q = 0; q < 4; ++q)
                ATOMIC_ST32(thxU32 + (size_t)grp * 2048 + (lq * 4 + q) * 256 + (jglob >> 1), pk[q]);
        }
    }
    __syncthreads();   // vmcnt(0) drain: th stores globally visible
    if (tid == 0) ATOMIC_ST32(flgA + (grp * 8 + member) * 32, 1u);

    for (int s = 0; s < TSEQ; ++s) {
        // u prefetch (own slice, written by u_gemm; same-thread overwrite later;
        // values latched by the pre-M1 __syncthreads vmcnt drain before publish)
        float uR[4] = {0.f, 0.f, 0.f, 0.f};
        if (l < 32) {
            #pragma unroll
            for (int q = 0; q < 4; ++q)
                uR[q] = b2f(utp[((size_t)(s * NBAT + rows0 + lq * 4 + q)) * NST + jglob]);
        }
        // ---- barrier A: all members published th(s) + dc(s-1) ----
        if (tid < 8) {
            unsigned* fp = flgA + (grp * 8 + tid) * 32;
            while (ATOMIC_LD32(fp) < (unsigned)(s + 1)) __builtin_amdgcn_s_sleep(1);
        }
        __syncthreads();
        // ---- gather: th (8KB bf16) + dc partials (16KB f32), all atomic ----
        {
            const int row = tid >> 5, ch = tid & 31;
            ull tv[4];
            ull* src = thxU64 + (size_t)grp * 1024 + row * 128 + ch * 4;
            #pragma unroll
            for (int i = 0; i < 4; ++i) tv[i] = ATOMIC_LD64(src + i);
            ull dv[8];
            #pragma unroll
            for (int m = 0; m < 8; ++m)
                dv[m] = ATOMIC_LD64(dcU64 + (size_t)(grp * 8 + m) * 256 + cr * 32 + (cc >> 1));
            // c update
            float d0 = 0.f, d1 = 0.f;
            #pragma unroll
            for (int m = 0; m < 8; ++m) {
                union { ull u; float f[2]; } cv; cv.u = dv[m];
                d0 += cv.f[0]; d1 += cv.f[1];
            }
            cM0 -= 0.1f * d0; cM1 -= 0.1f * d1;
            cS[cr * 72 + cc] = f2b(cM0);
            cS[cr * 72 + cc + 1] = f2b(cM1);
            // stage th
            ull* dst = reinterpret_cast<ull*>(&stage[row * 520 + ch * 16]);
            #pragma unroll
            for (int i = 0; i < 4; ++i) dst[i] = tv[i];
        }
        __syncthreads();
        // ---- M1: h_prior slice = 0.9h + 0.1(th@Wr^T + c@Wc^T + b_r) ----
        floatx4 acc = {0.f, 0.f, 0.f, 0.f};
        #pragma unroll
        for (int kt = 0; kt < 16; ++kt) {
            short8 a = {0, 0, 0, 0, 0, 0, 0, 0};
            if (lm < 8) a = *reinterpret_cast<const short8*>(&stage[lm * 520 + kt * 32 + lq * 8]);
            short8 b = *reinterpret_cast<const short8*>(&wrF[((w * 16 + kt) * 64 + l) * 8]);
            acc = __builtin_amdgcn_mfma_f32_16x16x32_bf16(a, b, acc, 0, 0, 0);
        }
        #pragma unroll
        for (int kt = 0; kt < 2; ++kt) {
            short8 a = {0, 0, 0, 0, 0, 0, 0, 0};
            if (lm < 8) a = *reinterpret_cast<const short8*>(&cS[lm * 72 + kt * 32 + lq * 8]);
            short8 b = *reinterpret_cast<const short8*>(&wcF[((w * 2 + kt) * 64 + l) * 8]);
            acc = __builtin_amdgcn_mfma_f32_16x16x32_bf16(a, b, acc, 0, 0, 0);
        }
        float hPr[4], tp[4];
        #pragma unroll
        for (int q = 0; q < 4; ++q) {
            hPr[q] = 0.9f * hP[q] + 0.1f * (acc[q] + br_l);
            tp[q] = tanhf(hPr[q]);
        }
        // ---- publish tp into utp[s] (atomic; peers gather from there) ----
        {
            unsigned pk[4];
            #pragma unroll
            for (int q = 0; q < 4; ++q) {
                unsigned m_ = f2b(tp[q]);
                unsigned p_ = __shfl_xor(m_, 1);
                pk[q] = m_ | (p_ << 16);
            }
            if (l < 32 && !(l & 1)) {
                #pragma unroll
                for (int q = 0; q < 4; ++q)
                    ATOMIC_ST32(utpU32 + ((size_t)(s * NBAT) + rows0 + lq * 4 + q) * 256 + (jglob >> 1), pk[q]);
            }
        }
        // ---- barrier B: tp ready ----
        __syncthreads();   // vmcnt(0) drain
        if (tid == 0) ATOMIC_ST32(flgB + (grp * 8 + member) * 32, (unsigned)(s + 1));
        if (tid < 8) {
            unsigned* fp = flgB + (grp * 8 + tid) * 32;
            while (ATOMIC_LD32(fp) < (unsigned)(s + 1)) __builtin_amdgcn_s_sleep(1);
        }
        __syncthreads();
        // ---- gather tp from utp[s] ----
        {
            const int row = tid >> 5, ch = tid & 31;
            ull tv[4];
            ull* src = utpU64 + ((size_t)(s * NBAT) + rows0 + row) * 128 + ch * 4;
            #pragma unroll
            for (int i = 0; i < 4; ++i) tv[i] = ATOMIC_LD64(src + i);
            ull* dst = reinterpret_cast<ull*>(&stage[row * 520 + ch * 16]);
            #pragma unroll
            for (int i = 0; i < 4; ++i) dst[i] = tv[i];
        }
        __syncthreads();
        // ---- M2: g slice = tp@Wq + u_t ----
        floatx4 ac2 = {0.f, 0.f, 0.f, 0.f};
        #pragma unroll
        for (int kt = 0; kt < 16; ++kt) {
            short8 a = {0, 0, 0, 0, 0, 0, 0, 0};
            if (lm < 8) a = *reinterpret_cast<const short8*>(&stage[lm * 520 + kt * 32 + lq * 8]);
            short8 b = *reinterpret_cast<const short8*>(&wqF[((w * 16 + kt) * 64 + l) * 8]);
            ac2 = __builtin_amdgcn_mfma_f32_16x16x32_bf16(a, b, ac2, 0, 0, 0);
        }
        float eH[4];
        #pragma unroll
        for (int q = 0; q < 4; ++q) {
            float g = ac2[q] + uR[q];
            eH[q] = 0.1f * (1.f - tp[q] * tp[q]) * g;
            hP[q] = hPr[q] - eH[q];
        }
        if (l < 32) {
            #pragma unroll
            for (int q = 0; q < 4; ++q) errS[(lq * 4 + q) * 68 + jloc] = eH[q];
        }
        __syncthreads();
        // ---- dc partial = e_h(slice) @ Wc(slice); atomic 8B publish ----
        {
            float s0 = 0.f, s1 = 0.f;
            #pragma unroll 8
            for (int j = 0; j < 64; ++j) {
                float e = errS[cr * 68 + j];
                s0 += e * b2f(wcR[j * 64 + cc]);
                s1 += e * b2f(wcR[j * 64 + cc + 1]);
            }
            union { float f[2]; ull u; } pv; pv.f[0] = s0; pv.f[1] = s1;
            ATOMIC_ST64(dcU64 + (size_t)(grp * 8 + member) * 256 + cr * 32 + (cc >> 1), pv.u);
        }
        // ---- publish th(new) ----
        {
            unsigned pk[4];
            #pragma unroll
            for (int q = 0; q < 4; ++q) {
                unsigned m_ = f2b(tanhf(hP[q]));
                unsigned p_ = __shfl_xor(m_, 1);
                pk[q] = m_ | (p_ << 16);
            }
            if (l < 32 && !(l & 1)) {
                #pragma unroll
                for (int q = 0; q < 4; ++q)
                    ATOMIC_ST32(thxU32 + (size_t)grp * 2048 + (lq * 4 + q) * 256 + (jglob >> 1), pk[q]);
            }
        }
        __syncthreads();   // vmcnt(0) drain: th + dc stores globally visible
        if (tid == 0) ATOMIC_ST32(flgA + (grp * 8 + member) * 32, (unsigned)(s + 2));
    }
}

extern "C" void kernel_launch(void* const* d_in, const int* in_sizes, int n_in,
                              void* d_out, int out_size, void* d_ws, size_t ws_size,
                              hipStream_t stream) {
    const float* x      = (const float*)d_in[0];
    const float* c_init = (const float*)d_in[1];
    const float* h_init = (const float*)d_in[2];
    const float* w_o    = (const float*)d_in[3];
    const float* b_o    = (const float*)d_in[4];
    const float* w_c    = (const float*)d_in[5];
    const float* w_r    = (const float*)d_in[6];
    const float* b_r    = (const float*)d_in[7];

    char* wsb = (char*)d_ws;
    unsigned short* utp = (unsigned short*)(wsb + OFF_UTP);
    unsigned short* wq  = (unsigned short*)(wsb + OFF_WQ);
    unsigned short* thx = (unsigned short*)(wsb + OFF_THX);
    float*          dcx = (float*)(wsb + OFF_DCX);
    unsigned*       flg = (unsigned*)(wsb + OFF_FLG);

    hipMemsetAsync(wsb + OFF_THX, 0, SZ_ZERO, stream);

    wq_kernel<<<dim3((NST * NST) / 256), dim3(256), 0, stream>>>(w_o, wq);
    u_gemm<<<dim3((TSEQ * NBAT) / 64, NST / 64), dim3(256), 0, stream>>>(x, w_o, b_o, utp);

    void* args[] = { (void*)&c_init, (void*)&h_init, (void*)&w_r, (void*)&b_r,
                     (void*)&w_c, (void*)&utp, (void*)&wq, (void*)&thx,
                     (void*)&dcx, (void*)&flg };
    hipLaunchCooperativeKernel((void*)loop_kernel, dim3(256), dim3(256), args, 0, stream);

    err_gemm<<<dim3((TSEQ * NBAT) / 64, NOUT / 64), dim3(256), 0, stream>>>(utp, w_o, b_o, x, (float*)d_out);
}